// Round 1
// baseline (191.985 us; speedup 1.0000x reference)
//
#include <hip/hip_runtime.h>
#include <hip/hip_bf16.h>
#include <math.h>

#define S_LEN 2048
#define DKV 64
#define NQT (S_LEN / 64)
#define NBH 32

typedef __attribute__((ext_vector_type(8))) short bf16x8;
typedef __attribute__((ext_vector_type(4))) float f32x4;

__device__ __forceinline__ short f2bf(float f) {
    union { float f; unsigned u; } x; x.f = f;
    unsigned r = (x.u + 0x7FFFu + ((x.u >> 16) & 1u)) >> 16;
    return (short)r;
}

__global__ __launch_bounds__(256)
void attn_fwd(const float* __restrict__ Q, const float* __restrict__ K,
              const float* __restrict__ V, float* __restrict__ O) {
    const int tid = threadIdx.x;
    const int l   = tid & 63;
    const int w   = tid >> 6;
    const int g   = l >> 4;     // 0..3
    const int r16 = l & 15;     // 0..15
    const int qt  = blockIdx.x;
    const int bh  = blockIdx.y;
    const int q0  = qt * 64;

    __shared__ short Kl[64 * 64];      // K tile, row-major bf16, XOR-swizzled (8 KB)
    __shared__ short Vt[64 * 64];      // V^T tile, row=vdim, col=key, swizzled (8 KB)
    __shared__ short Pl[4][16 * 64];   // per-wave P tile, row=q (16), col=key (64) (8 KB)

    const float* Qp = Q + (size_t)bh * S_LEN * DKV;
    const float* Kp = K + (size_t)bh * S_LEN * DKV;
    const float* Vp = V + (size_t)bh * S_LEN * DKV;

    // ---- Q fragments (16 rows per wave), kept in registers as bf16 A-frags ----
    bf16x8 qf[2];
    {
        const int row = q0 + w * 16 + r16;
        const float* qr = Qp + (size_t)row * DKV;
#pragma unroll
        for (int c = 0; c < 2; ++c) {
            const int k0 = c * 32 + g * 8;
            float4 f0 = *(const float4*)(qr + k0);
            float4 f1 = *(const float4*)(qr + k0 + 4);
            bf16x8 t;
            t[0] = f2bf(f0.x); t[1] = f2bf(f0.y); t[2] = f2bf(f0.z); t[3] = f2bf(f0.w);
            t[4] = f2bf(f1.x); t[5] = f2bf(f1.y); t[6] = f2bf(f1.z); t[7] = f2bf(f1.w);
            qf[c] = t;
        }
    }

    float m[4], lsum[4];
    f32x4 oacc[4];
#pragma unroll
    for (int r = 0; r < 4; ++r) { m[r] = -3.0e38f; lsum[r] = 0.0f; }
#pragma unroll
    for (int vt = 0; vt < 4; ++vt) oacc[vt] = (f32x4){0.f, 0.f, 0.f, 0.f};

    const float SCALE = 0.125f * 1.4426950408889634f;  // 1/sqrt(64) * log2(e)

    for (int kvb = 0; kvb <= qt; ++kvb) {
        const int kv0 = kvb * 64;
        __syncthreads();  // previous tile fully consumed by all waves

        // ---- stage K (row-major, swizzled) and V (transposed, swizzled) ----
#pragma unroll
        for (int i = 0; i < 4; ++i) {
            const int idx = i * 256 + tid;   // 0..1023 float4-chunks
            const int row = idx >> 4;        // key 0..63
            const int c4  = idx & 15;        // float4 within row
            float4 kk = *(const float4*)(Kp + (size_t)(kv0 + row) * DKV + c4 * 4);
            {
                int byteoff = row * 128 + c4 * 8;
                byteoff ^= (row & 7) << 4;
                short4 v4;
                v4.x = f2bf(kk.x); v4.y = f2bf(kk.y); v4.z = f2bf(kk.z); v4.w = f2bf(kk.w);
                *(short4*)((char*)Kl + byteoff) = v4;
            }
            float4 vv = *(const float4*)(Vp + (size_t)(kv0 + row) * DKV + c4 * 4);
#pragma unroll
            for (int j = 0; j < 4; ++j) {
                const int vd = c4 * 4 + j;
                int byteoff = vd * 128 + row * 2;
                byteoff ^= (vd & 7) << 4;
                const float fv = (j == 0) ? vv.x : (j == 1) ? vv.y : (j == 2) ? vv.z : vv.w;
                *(short*)((char*)Vt + byteoff) = f2bf(fv);
            }
        }
        __syncthreads();

        // ---- QK^T: 4 key-subtiles x 2 k-chunks ----
        f32x4 sacc[4];
#pragma unroll
        for (int t = 0; t < 4; ++t) sacc[t] = (f32x4){0.f, 0.f, 0.f, 0.f};
#pragma unroll
        for (int c = 0; c < 2; ++c) {
#pragma unroll
            for (int t = 0; t < 4; ++t) {
                const int key = t * 16 + r16;
                int byteoff = key * 128 + c * 64 + g * 16;
                byteoff ^= (key & 7) << 4;
                bf16x8 bk = *(const bf16x8*)((char*)Kl + byteoff);
                sacc[t] = __builtin_amdgcn_mfma_f32_16x16x32_bf16(qf[c], bk, sacc[t], 0, 0, 0);
            }
        }

        // ---- scale + causal mask + row-max ----
        const bool diag = (kvb == qt);
        float sv[4][4];
        float pmax[4];
#pragma unroll
        for (int r = 0; r < 4; ++r) pmax[r] = -3.0e38f;
#pragma unroll
        for (int t = 0; t < 4; ++t) {
#pragma unroll
            for (int r = 0; r < 4; ++r) {
                float s = sacc[t][r] * SCALE;
                if (diag) {
                    const int key  = 16 * t + r16;       // within block (kv0 == q0)
                    const int qrow = 16 * w + 4 * g + r;  // within tile
                    if (key > qrow) s = -3.0e38f;
                }
                sv[t][r] = s;
                pmax[r] = fmaxf(pmax[r], s);
            }
        }
#pragma unroll
        for (int r = 0; r < 4; ++r) {
            float v = pmax[r];
            v = fmaxf(v, __shfl_xor(v, 1));
            v = fmaxf(v, __shfl_xor(v, 2));
            v = fmaxf(v, __shfl_xor(v, 4));
            v = fmaxf(v, __shfl_xor(v, 8));
            pmax[r] = v;
        }

        // ---- online-softmax update ----
        float sf[4];
#pragma unroll
        for (int r = 0; r < 4; ++r) {
            const float mn = fmaxf(m[r], pmax[r]);
            sf[r] = exp2f(m[r] - mn);
            m[r]  = mn;
        }
        float rs[4] = {0.f, 0.f, 0.f, 0.f};
        char* pbase = (char*)(&Pl[w][0]);
#pragma unroll
        for (int t = 0; t < 4; ++t) {
#pragma unroll
            for (int r = 0; r < 4; ++r) {
                const float p = exp2f(sv[t][r] - m[r]);
                rs[r] += p;
                const int qrow = 4 * g + r;
                const int key  = 16 * t + r16;
                int byteoff = qrow * 128 + key * 2;
                byteoff ^= (qrow & 7) << 4;
                *(short*)(pbase + byteoff) = f2bf(p);
            }
        }
#pragma unroll
        for (int r = 0; r < 4; ++r) {
            float v = rs[r];
            v += __shfl_xor(v, 1);
            v += __shfl_xor(v, 2);
            v += __shfl_xor(v, 4);
            v += __shfl_xor(v, 8);
            lsum[r] = lsum[r] * sf[r] + v;
        }
#pragma unroll
        for (int vt = 0; vt < 4; ++vt)
#pragma unroll
            for (int r = 0; r < 4; ++r) oacc[vt][r] *= sf[r];

        // own-wave P writes must land before PV reads
        asm volatile("s_waitcnt lgkmcnt(0)" ::: "memory");

        // ---- PV: O += P * V ----
#pragma unroll
        for (int c = 0; c < 2; ++c) {
            int poff = r16 * 128 + c * 64 + g * 16;
            poff ^= (r16 & 7) << 4;
            bf16x8 ap = *(const bf16x8*)(pbase + poff);
#pragma unroll
            for (int vt = 0; vt < 4; ++vt) {
                const int vd = 16 * vt + r16;
                int voff = vd * 128 + c * 64 + g * 16;
                voff ^= (vd & 7) << 4;
                bf16x8 bv = *(const bf16x8*)((char*)Vt + voff);
                oacc[vt] = __builtin_amdgcn_mfma_f32_16x16x32_bf16(ap, bv, oacc[vt], 0, 0, 0);
            }
        }
    }

    // ---- epilogue: O / l ----
    float inv[4];
#pragma unroll
    for (int r = 0; r < 4; ++r) inv[r] = 1.0f / lsum[r];
    float* Op = O + (size_t)bh * S_LEN * DKV;
#pragma unroll
    for (int vt = 0; vt < 4; ++vt) {
#pragma unroll
        for (int r = 0; r < 4; ++r) {
            const int qrow = q0 + 16 * w + 4 * g + r;
            const int col  = 16 * vt + r16;
            Op[(size_t)qrow * DKV + col] = oacc[vt][r] * inv[r];
        }
    }
}

extern "C" void kernel_launch(void* const* d_in, const int* in_sizes, int n_in,
                              void* d_out, int out_size, void* d_ws, size_t ws_size,
                              hipStream_t stream) {
    const float* Q = (const float*)d_in[0];
    const float* K = (const float*)d_in[1];
    const float* V = (const float*)d_in[2];
    // d_in[3] (attn_mask) is a fixed causal triu(k=1) mask -> applied analytically.
    float* O = (float*)d_out;
    dim3 grid(NQT, NBH);
    attn_fwd<<<grid, 256, 0, stream>>>(Q, K, V, O);
}

// Round 2
// 142.219 us; speedup vs baseline: 1.3499x; 1.3499x over previous
//
#include <hip/hip_runtime.h>
#include <hip/hip_bf16.h>
#include <math.h>

#define S_LEN 2048
#define DKV 64
#define NQT (S_LEN / 64)
#define NBH 32
#define TILE_SH 4096  // shorts per 64x64 bf16 tile image (8 KB)

typedef __attribute__((ext_vector_type(8))) short bf16x8;
typedef __attribute__((ext_vector_type(4))) float f32x4;

__device__ __forceinline__ short f2bf(float f) {
    union { float f; unsigned u; } x; x.f = f;
    unsigned r = (x.u + 0x7FFFu + ((x.u >> 16) & 1u)) >> 16;
    return (short)r;
}

#define GLOAD_LDS16(g, s)                                                        \
    __builtin_amdgcn_global_load_lds(                                            \
        (const __attribute__((address_space(1))) unsigned*)(g),                  \
        (__attribute__((address_space(3))) unsigned*)(s), 16, 0, 0)

// ---------------------------------------------------------------------------
// Prep: K -> bf16 swizzled LDS-image tiles; V -> transposed bf16 swizzled
// LDS-image tiles. Image layout matches exactly what the attention kernel
// wants resident in LDS, so staging becomes pure global_load_lds.
// K image:  byteoff(row=key, col) = (row*128 + col*2) ^ ((row&7)<<4)
// V image:  byteoff(row=vd,  key) = (vd*128  + key*2) ^ ((vd&7)<<4)
// ---------------------------------------------------------------------------
__global__ __launch_bounds__(256)
void prep_kv(const float* __restrict__ K, const float* __restrict__ V,
             short* __restrict__ wsK, short* __restrict__ wsV) {
    const int tile = blockIdx.x, bh = blockIdx.y, tid = threadIdx.x;
    const float* Kp = K + ((size_t)bh * S_LEN + tile * 64) * DKV;
    const float* Vp = V + ((size_t)bh * S_LEN + tile * 64) * DKV;
    short* outK = wsK + ((size_t)bh * NQT + tile) * TILE_SH;
    short* outV = wsV + ((size_t)bh * NQT + tile) * TILE_SH;

    __shared__ short Vl[64 * 64];  // linear V tile [key][vd]

#pragma unroll
    for (int i = 0; i < 2; ++i) {
        const int chunk = i * 256 + tid;      // 0..511, 8 shorts each
        const int row = chunk >> 3, c8 = chunk & 7;
        const float* ks = Kp + row * DKV + c8 * 8;
        float4 a = *(const float4*)ks, b = *(const float4*)(ks + 4);
        bf16x8 t;
        t[0] = f2bf(a.x); t[1] = f2bf(a.y); t[2] = f2bf(a.z); t[3] = f2bf(a.w);
        t[4] = f2bf(b.x); t[5] = f2bf(b.y); t[6] = f2bf(b.z); t[7] = f2bf(b.w);
        *(bf16x8*)((char*)outK + ((row * 128 + c8 * 16) ^ ((row & 7) << 4))) = t;

        const float* vs = Vp + row * DKV + c8 * 8;
        float4 c = *(const float4*)vs, d = *(const float4*)(vs + 4);
        bf16x8 u;
        u[0] = f2bf(c.x); u[1] = f2bf(c.y); u[2] = f2bf(c.z); u[3] = f2bf(c.w);
        u[4] = f2bf(d.x); u[5] = f2bf(d.y); u[6] = f2bf(d.z); u[7] = f2bf(d.w);
        *(bf16x8*)&Vl[chunk * 8] = u;
    }
    __syncthreads();
#pragma unroll
    for (int i = 0; i < 2; ++i) {
        const int chunk = i * 256 + tid;
        const int vd = chunk >> 3, k8 = chunk & 7;
        bf16x8 t;
#pragma unroll
        for (int j = 0; j < 8; ++j) t[j] = Vl[(k8 * 8 + j) * 64 + vd];
        *(bf16x8*)((char*)outV + ((vd * 128 + k8 * 16) ^ ((vd & 7) << 4))) = t;
    }
}

// ---------------------------------------------------------------------------
// Flash attention, causal. 64 Q-rows per block, 4 waves (16 rows each),
// KV-block 64, double-buffered LDS staged via global_load_lds from images.
// ---------------------------------------------------------------------------
__global__ __launch_bounds__(256)
void attn_fwd(const float* __restrict__ Q, const short* __restrict__ wsK,
              const short* __restrict__ wsV, float* __restrict__ O) {
    const int tid = threadIdx.x;
    const int l   = tid & 63;
    const int w   = tid >> 6;
    const int g   = l >> 4;
    const int r16 = l & 15;
    const int qt  = blockIdx.x;
    const int bh  = blockIdx.y;
    const int q0  = qt * 64;

    __shared__ short Kl[2][TILE_SH];
    __shared__ short Vt[2][TILE_SH];
    __shared__ short Pl[4][16 * 64];

    const float SCALE = 0.125f * 1.4426950408889634f;  // 1/sqrt(64)*log2(e)

    // Q fragments, pre-scaled so scores come out in log2 domain directly.
    bf16x8 qf[2];
    {
        const int row = q0 + w * 16 + r16;
        const float* qr = Q + ((size_t)bh * S_LEN + row) * DKV;
#pragma unroll
        for (int c = 0; c < 2; ++c) {
            const int k0 = c * 32 + g * 8;
            float4 f0 = *(const float4*)(qr + k0);
            float4 f1 = *(const float4*)(qr + k0 + 4);
            bf16x8 t;
            t[0] = f2bf(f0.x * SCALE); t[1] = f2bf(f0.y * SCALE);
            t[2] = f2bf(f0.z * SCALE); t[3] = f2bf(f0.w * SCALE);
            t[4] = f2bf(f1.x * SCALE); t[5] = f2bf(f1.y * SCALE);
            t[6] = f2bf(f1.z * SCALE); t[7] = f2bf(f1.w * SCALE);
            qf[c] = t;
        }
    }

    const short* gKbase = wsK + (size_t)bh * NQT * TILE_SH;
    const short* gVbase = wsV + (size_t)bh * NQT * TILE_SH;
    const int woff = w * 2048;   // this wave's 2KB slice of the 8KB image
    const int loff = l * 16;

#define STAGE(buf, kvb)                                                     \
    do {                                                                    \
        const char* gK = (const char*)(gKbase + (size_t)(kvb)*TILE_SH);     \
        const char* gV = (const char*)(gVbase + (size_t)(kvb)*TILE_SH);     \
        char* lK = (char*)&Kl[buf][0] + woff;                               \
        char* lV = (char*)&Vt[buf][0] + woff;                               \
        GLOAD_LDS16(gK + woff + loff, lK);                                  \
        GLOAD_LDS16(gK + woff + 1024 + loff, lK + 1024);                    \
        GLOAD_LDS16(gV + woff + loff, lV);                                  \
        GLOAD_LDS16(gV + woff + 1024 + loff, lV + 1024);                    \
    } while (0)

    float m[4], lsum[4];
    f32x4 oacc[4];
#pragma unroll
    for (int r = 0; r < 4; ++r) { m[r] = -3.0e38f; lsum[r] = 0.0f; }
#pragma unroll
    for (int vt = 0; vt < 4; ++vt) oacc[vt] = (f32x4){0.f, 0.f, 0.f, 0.f};

    STAGE(0, 0);
    asm volatile("s_waitcnt vmcnt(0)" ::: "memory");
    __syncthreads();

    int cur = 0;
    for (int kvb = 0; kvb <= qt; ++kvb) {
        if (kvb < qt) STAGE(cur ^ 1, kvb + 1);   // prefetch flies under compute

        const char* kbase = (const char*)&Kl[cur][0];
        const char* vbase = (const char*)&Vt[cur][0];

        // ---- QK^T (already log2-scaled via Q) ----
        f32x4 sacc[4];
#pragma unroll
        for (int t = 0; t < 4; ++t) sacc[t] = (f32x4){0.f, 0.f, 0.f, 0.f};
#pragma unroll
        for (int c = 0; c < 2; ++c) {
#pragma unroll
            for (int t = 0; t < 4; ++t) {
                const int key = t * 16 + r16;
                const int byteoff = (key * 128 + c * 64 + g * 16) ^ ((key & 7) << 4);
                bf16x8 bk = *(const bf16x8*)(kbase + byteoff);
                sacc[t] = __builtin_amdgcn_mfma_f32_16x16x32_bf16(qf[c], bk, sacc[t], 0, 0, 0);
            }
        }

        // ---- causal mask + row-max ----
        const bool diag = (kvb == qt);
        float sv[4][4], pmax[4];
#pragma unroll
        for (int r = 0; r < 4; ++r) pmax[r] = -3.0e38f;
#pragma unroll
        for (int t = 0; t < 4; ++t) {
#pragma unroll
            for (int r = 0; r < 4; ++r) {
                float s = sacc[t][r];
                if (diag) {
                    const int key  = 16 * t + r16;
                    const int qrow = 16 * w + 4 * g + r;
                    if (key > qrow) s = -3.0e38f;
                }
                sv[t][r] = s;
                pmax[r] = fmaxf(pmax[r], s);
            }
        }
#pragma unroll
        for (int r = 0; r < 4; ++r) {
            float v = pmax[r];
            v = fmaxf(v, __shfl_xor(v, 1));
            v = fmaxf(v, __shfl_xor(v, 2));
            v = fmaxf(v, __shfl_xor(v, 4));
            v = fmaxf(v, __shfl_xor(v, 8));
            pmax[r] = v;
        }

        // ---- online softmax with defer-max (T13, THR=8 in log2 domain) ----
        bool within = true;
#pragma unroll
        for (int r = 0; r < 4; ++r) within &= (pmax[r] <= m[r] + 8.0f);
        const bool skip = __all(within);

        float sf[4];
        if (!skip) {
#pragma unroll
            for (int r = 0; r < 4; ++r) {
                const float mn = fmaxf(m[r], pmax[r]);
                sf[r] = exp2f(m[r] - mn);
                m[r]  = mn;
            }
        }

        float rs[4] = {0.f, 0.f, 0.f, 0.f};
        char* pbase = (char*)(&Pl[w][0]);
#pragma unroll
        for (int t = 0; t < 4; ++t) {
#pragma unroll
            for (int r = 0; r < 4; ++r) {
                const float p = exp2f(sv[t][r] - m[r]);
                rs[r] += p;
                const int qrow = 4 * g + r;
                const int key  = 16 * t + r16;
                const int byteoff = (qrow * 128 + key * 2) ^ ((qrow & 7) << 4);
                *(short*)(pbase + byteoff) = f2bf(p);
            }
        }
#pragma unroll
        for (int r = 0; r < 4; ++r) {
            float v = rs[r];
            v += __shfl_xor(v, 1);
            v += __shfl_xor(v, 2);
            v += __shfl_xor(v, 4);
            v += __shfl_xor(v, 8);
            lsum[r] = skip ? (lsum[r] + v) : (lsum[r] * sf[r] + v);
        }
        if (!skip) {
#pragma unroll
            for (int vt = 0; vt < 4; ++vt)
#pragma unroll
                for (int r = 0; r < 4; ++r) oacc[vt][r] *= sf[r];
        }

        // ---- PV: O += P * V (own-wave LDS RAW is in-order, safe) ----
#pragma unroll
        for (int c = 0; c < 2; ++c) {
            const int poff = (r16 * 128 + c * 64 + g * 16) ^ ((r16 & 7) << 4);
            bf16x8 ap = *(const bf16x8*)(pbase + poff);
#pragma unroll
            for (int vt = 0; vt < 4; ++vt) {
                const int vd = 16 * vt + r16;
                const int voff = (vd * 128 + c * 64 + g * 16) ^ ((vd & 7) << 4);
                bf16x8 bv = *(const bf16x8*)(vbase + voff);
                oacc[vt] = __builtin_amdgcn_mfma_f32_16x16x32_bf16(ap, bv, oacc[vt], 0, 0, 0);
            }
        }

        asm volatile("s_waitcnt vmcnt(0)" ::: "memory");
        __syncthreads();   // prefetch landed + all waves done with cur
        cur ^= 1;
    }

    // ---- epilogue ----
    float inv[4];
#pragma unroll
    for (int r = 0; r < 4; ++r) inv[r] = 1.0f / lsum[r];
    float* Op = O + (size_t)bh * S_LEN * DKV;
#pragma unroll
    for (int vt = 0; vt < 4; ++vt) {
#pragma unroll
        for (int r = 0; r < 4; ++r) {
            const int qrow = q0 + 16 * w + 4 * g + r;
            const int col  = 16 * vt + r16;
            Op[(size_t)qrow * DKV + col] = oacc[vt][r] * inv[r];
        }
    }
}

extern "C" void kernel_launch(void* const* d_in, const int* in_sizes, int n_in,
                              void* d_out, int out_size, void* d_ws, size_t ws_size,
                              hipStream_t stream) {
    const float* Q = (const float*)d_in[0];
    const float* K = (const float*)d_in[1];
    const float* V = (const float*)d_in[2];
    // d_in[3] (attn_mask) is the fixed causal triu(k=1) mask -> applied analytically.
    float* O = (float*)d_out;

    short* wsK = (short*)d_ws;                                   // 8 MiB
    short* wsV = wsK + (size_t)NBH * NQT * TILE_SH;              // 8 MiB

    dim3 grid(NQT, NBH);
    prep_kv<<<grid, 256, 0, stream>>>(K, V, wsK, wsV);
    attn_fwd<<<grid, 256, 0, stream>>>(Q, wsK, wsV, O);
}